// Round 1
// 190.536 us; speedup vs baseline: 1.0819x; 1.0819x over previous
//
#include <hip/hip_runtime.h>

#define D 64
#define NPB 128              // nodes per bucket (dstLocal: 7 bits)
#define NPB_SHIFT 7
#define MAXB 1024            // bound on bucket count B = ceil(N/NPB)
#define SCATTER_T 256
#define CHUNK_MAX 4704       // max edges staged per scatter block (LDS-sized)
#define CAP 2560             // max bucket edges staged in sort_gather LDS
#define GT 512               // sort_gather block size (8 waves)

// round-to-nearest-even fp32 -> bf16 (values are finite/normal here)
__device__ inline unsigned f2bf(float f) {
    unsigned u = __float_as_uint(f);
    return (u + 0x7FFFu + ((u >> 16) & 1u)) >> 16;
}

// ---------------------------------------------------------------------------
// zero helpers (ws is poisoned 0xAA every launch)
// ---------------------------------------------------------------------------
__global__ void zero_i_kernel(int* __restrict__ p, int n) {
    int i = blockIdx.x * blockDim.x + threadIdx.x;
    if (i < n) p[i] = 0;
}
__global__ void zero_f4_kernel(float4* __restrict__ p, int n4) {
    int i = blockIdx.x * blockDim.x + threadIdx.x;
    if (i < n4) p[i] = make_float4(0.f, 0.f, 0.f, 0.f);
}

// ---------------------------------------------------------------------------
// bucket histogram: LDS-staged, then one global atomic per (block,bucket)
// ---------------------------------------------------------------------------
__global__ __launch_bounds__(SCATTER_T) void hist_bucket_kernel(const int* __restrict__ dst,
                                                                int* __restrict__ cnt,
                                                                int E, int B) {
    __shared__ int lc[MAXB];
    for (int i = threadIdx.x; i < B; i += blockDim.x) lc[i] = 0;
    __syncthreads();
    int chunk = (E + gridDim.x - 1) / gridDim.x;
    int lo = blockIdx.x * chunk, hi = min(lo + chunk, E);
    for (int e = lo + threadIdx.x; e < hi; e += blockDim.x)
        atomicAdd(&lc[dst[e] >> NPB_SHIFT], 1);
    __syncthreads();
    for (int i = threadIdx.x; i < B; i += blockDim.x)
        if (lc[i]) atomicAdd(&cnt[i], lc[i]);
}

// ---------------------------------------------------------------------------
// exclusive scan of bucket counts (single block of MAXB threads)
// writes bucketStart[0..B], cursor[0..B)
// ---------------------------------------------------------------------------
__global__ __launch_bounds__(MAXB) void scan_bucket_kernel(const int* __restrict__ cnt,
                                                           int* __restrict__ bucketStart,
                                                           int* __restrict__ cursor,
                                                           int B, int E) {
    __shared__ int sd[MAXB];
    int t = threadIdx.x;
    sd[t] = (t < B) ? cnt[t] : 0;
    __syncthreads();
    for (int st = 1; st < MAXB; st <<= 1) {
        int v = (t >= st) ? sd[t - st] : 0;
        __syncthreads();
        sd[t] += v;
        __syncthreads();
    }
    if (t < B) {
        int ex = (t == 0) ? 0 : sd[t - 1];
        bucketStart[t] = ex;
        cursor[t] = ex;
    }
    if (t == 0) bucketStart[B] = E;
}

// ---------------------------------------------------------------------------
// bucket scatter v2: LDS counting sort of the chunk, then COALESCED writes.
// Pass A: hist -> local excl scan (lpre) -> reserve global ranges (lbase).
// Pass B: place packed entries at their locally-sorted LDS slot.
// Pass C: walk local sorted order; consecutive i within a bucket map to
// consecutive adjB addresses -> runs of ~48B instead of random 8B stores.
// Packing: x = src | dstLocal<<20, y = w bits.
// ---------------------------------------------------------------------------
__global__ __launch_bounds__(SCATTER_T) void bucket_scatter_kernel(
        const int* __restrict__ src, const int* __restrict__ dst,
        const float* __restrict__ w, int* __restrict__ cursor,
        int2* __restrict__ adjB, int E, int B) {
    __shared__ int lc[MAXB];
    __shared__ int lpre[MAXB];
    __shared__ int lbase[MAXB];
    __shared__ int lfill[MAXB];
    __shared__ int sums[SCATTER_T];
    __shared__ unsigned short sb[CHUNK_MAX];
    __shared__ int2 stage[CHUNK_MAX];

    int t = threadIdx.x;
    int chunk = (E + gridDim.x - 1) / gridDim.x;   // <= CHUNK_MAX by launch calc
    int lo = blockIdx.x * chunk, hi = min(lo + chunk, E);
    int n = hi - lo;
    if (n <= 0) return;

    for (int i = t; i < MAXB; i += SCATTER_T) { lc[i] = 0; lfill[i] = 0; }
    __syncthreads();

    // A1: histogram
    for (int e = lo + t; e < hi; e += SCATTER_T)
        atomicAdd(&lc[dst[e] >> NPB_SHIFT], 1);
    __syncthreads();

    // A2: exclusive scan of lc[0..MAXB) -> lpre (4 elems/thread + H-S on 256)
    int s0 = lc[4 * t], s1 = lc[4 * t + 1], s2 = lc[4 * t + 2], s3 = lc[4 * t + 3];
    sums[t] = s0 + s1 + s2 + s3;
    __syncthreads();
    for (int st = 1; st < SCATTER_T; st <<= 1) {
        int v = (t >= st) ? sums[t - st] : 0;
        __syncthreads();
        sums[t] += v;
        __syncthreads();
    }
    int ex = (t == 0) ? 0 : sums[t - 1];
    lpre[4 * t]     = ex;
    lpre[4 * t + 1] = ex + s0;
    lpre[4 * t + 2] = ex + s0 + s1;
    lpre[4 * t + 3] = ex + s0 + s1 + s2;
    __syncthreads();

    // A3: reserve contiguous global ranges (1 atomic per nonempty bucket)
    for (int i = t; i < B; i += SCATTER_T) {
        int c = lc[i];
        lbase[i] = c ? atomicAdd(&cursor[i], c) : 0;
    }
    __syncthreads();

    // B: place into locally-sorted LDS slots
    for (int e = lo + t; e < hi; e += SCATTER_T) {
        int d = dst[e];
        int bkt = d >> NPB_SHIFT;
        int i = lpre[bkt] + atomicAdd(&lfill[bkt], 1);
        stage[i] = make_int2(src[e] | ((d & (NPB - 1)) << 20), __float_as_int(w[e]));
        sb[i] = (unsigned short)bkt;
    }
    __syncthreads();

    // C: coalesced write-out in locally-sorted order
    for (int i = t; i < n; i += SCATTER_T) {
        int bkt = sb[i];
        adjB[lbase[bkt] + (i - lpre[bkt])] = stage[i];
    }
}

// ---------------------------------------------------------------------------
// fused sort+gather: one block per bucket. Counting-sort the bucket's adjB
// slice into LDS (node-grouped), then each wave gathers 16 nodes:
// adjacency via LDS broadcast reads, proj rows 128B/half-wave from L2,
// 2-edge ILP, cross-half shfl reduce, coalesced float2 row store.
// Overflow past CAP (never for this input: mean 1536, CAP=2560) falls back
// to global float atomics after a syncthreads.
// ---------------------------------------------------------------------------
__global__ __launch_bounds__(GT) void sort_gather_kernel(
        const int2* __restrict__ adjB, const int* __restrict__ bucketStart,
        const unsigned* __restrict__ projU, float* __restrict__ out, int N) {
    __shared__ int cnt[NPB];
    __shared__ int pre[NPB];
    __shared__ int fill[NPB];
    __shared__ int2 ladj[CAP];

    int b = blockIdx.x;
    int beg = bucketStart[b], end = bucketStart[b + 1];
    int n = end - beg;
    int m = min(n, CAP);
    int t = threadIdx.x;

    if (t < NPB) { cnt[t] = 0; fill[t] = 0; }
    __syncthreads();
    for (int e = t; e < m; e += GT)
        atomicAdd(&cnt[((unsigned)adjB[beg + e].x) >> 20], 1);
    __syncthreads();
    if (t < NPB) pre[t] = cnt[t];
    __syncthreads();
    for (int st = 1; st < NPB; st <<= 1) {
        int v = (t < NPB && t >= st) ? pre[t - st] : 0;
        __syncthreads();
        if (t < NPB) pre[t] += v;
        __syncthreads();
    }
    for (int e = t; e < m; e += GT) {
        int2 a = adjB[beg + e];
        int dL = ((unsigned)a.x) >> 20;
        int pos = ((dL == 0) ? 0 : pre[dL - 1]) + atomicAdd(&fill[dL], 1);
        ladj[pos] = make_int2(a.x & 0xFFFFF, a.y);
    }
    __syncthreads();

    int wave = t >> 6;          // 0..7
    int lane = t & 63;
    int half = lane >> 5;
    int k = lane & 31;          // lane owns dims {2k, 2k+1}

#pragma unroll 1
    for (int i = 0; i < NPB / 8; ++i) {      // 16 nodes per wave
        int dL = wave * (NPB / 8) + i;
        int node = b * NPB + dL;
        if (node >= N) break;                // wave-uniform
        int rb = (dL == 0) ? 0 : pre[dL - 1];
        int re = pre[dL];
        float2 accA = make_float2(0.f, 0.f);
        float2 accB = make_float2(0.f, 0.f);
        int j = rb + half;
        for (; j + 2 < re; j += 4) {         // 2 edges in flight per half
            int2 a0 = ladj[j];
            int2 a1 = ladj[j + 2];
            float w0 = __int_as_float(a0.y);
            float w1 = __int_as_float(a1.y);
            unsigned p0 = projU[(size_t)a0.x * 32 + k];
            unsigned p1 = projU[(size_t)a1.x * 32 + k];
            accA.x += w0 * __uint_as_float(p0 << 16);
            accA.y += w0 * __uint_as_float(p0 & 0xFFFF0000u);
            accB.x += w1 * __uint_as_float(p1 << 16);
            accB.y += w1 * __uint_as_float(p1 & 0xFFFF0000u);
        }
        if (j < re) {
            int2 a0 = ladj[j];
            float w0 = __int_as_float(a0.y);
            unsigned p0 = projU[(size_t)a0.x * 32 + k];
            accA.x += w0 * __uint_as_float(p0 << 16);
            accA.y += w0 * __uint_as_float(p0 & 0xFFFF0000u);
        }
        float2 acc = make_float2(accA.x + accB.x, accA.y + accB.y);
        acc.x += __shfl(acc.x, lane ^ 32, 64);
        acc.y += __shfl(acc.y, lane ^ 32, 64);
        if (half == 0)
            *(float2*)&out[(size_t)node * D + 2 * k] = acc;  // 32 lanes x 8B
    }

    if (n > m) {                              // insurance path, never hot
        __syncthreads();                      // order stores before atomics
        int hw = t >> 5;                      // 16 half-waves
        for (int e = m + hw; e < n; e += GT / 32) {
            int2 a = adjB[beg + e];
            int dL = ((unsigned)a.x) >> 20;
            float wgt = __int_as_float(a.y);
            unsigned p = projU[(size_t)(a.x & 0xFFFFF) * 32 + k];
            size_t o = (size_t)(b * NPB + dL) * D + 2 * k;
            atomicAdd(&out[o],     wgt * __uint_as_float(p << 16));
            atomicAdd(&out[o + 1], wgt * __uint_as_float(p & 0xFFFF0000u));
        }
    }
}

// ---------------------------------------------------------------------------
// Tiled row GEMM -> bf16 packed proj. Block = 64 rows; A staged transposed
// in LDS; theta in LDS; thread computes 4x4 block.
// __launch_bounds__(256,4): cap VGPR at 128 (r5 post-mortem: the bf16-pack
// epilogue made the scheduler hoist the full k-unroll -> 252 VGPR, 9%
// occupancy, 60us). unroll 16 keeps ILP within the cap without spilling.
// ---------------------------------------------------------------------------
__global__ __launch_bounds__(256, 4) void rowgemm_bf16_kernel(const float* __restrict__ A,
                                                              const float* __restrict__ theta,
                                                              unsigned short* __restrict__ proj16,
                                                              int N) {
    __shared__ float th[D * D];
    __shared__ float at[D][68];
    int t = threadIdx.x;
    int rowBase = blockIdx.x * 64;

#pragma unroll
    for (int i = 0; i < 4; ++i) {
        int f = t + i * 256;
        ((float4*)th)[f] = ((const float4*)theta)[f];
    }
#pragma unroll
    for (int i = 0; i < 4; ++i) {
        int f = t + i * 256;
        int row = f >> 4;
        int kv = f & 15;
        float4 v = make_float4(0.f, 0.f, 0.f, 0.f);
        if (rowBase + row < N) v = *(const float4*)&A[(size_t)(rowBase + row) * D + kv * 4];
        at[kv * 4 + 0][row] = v.x;
        at[kv * 4 + 1][row] = v.y;
        at[kv * 4 + 2][row] = v.z;
        at[kv * 4 + 3][row] = v.w;
    }
    __syncthreads();

    int c0 = (t & 15) * 4;
    int r0 = (t >> 4) * 4;
    float4 acc0 = make_float4(0.f, 0.f, 0.f, 0.f);
    float4 acc1 = acc0, acc2 = acc0, acc3 = acc0;

#pragma unroll 16
    for (int k = 0; k < D; ++k) {
        float4 bv = *(const float4*)&th[k * D + c0];
        float4 av = *(const float4*)&at[k][r0];
        acc0.x += av.x * bv.x; acc0.y += av.x * bv.y; acc0.z += av.x * bv.z; acc0.w += av.x * bv.w;
        acc1.x += av.y * bv.x; acc1.y += av.y * bv.y; acc1.z += av.y * bv.z; acc1.w += av.y * bv.w;
        acc2.x += av.z * bv.x; acc2.y += av.z * bv.y; acc2.z += av.z * bv.z; acc2.w += av.z * bv.w;
        acc3.x += av.w * bv.x; acc3.y += av.w * bv.y; acc3.z += av.w * bv.z; acc3.w += av.w * bv.w;
    }

    float4 accs[4] = {acc0, acc1, acc2, acc3};
#pragma unroll
    for (int i = 0; i < 4; ++i) {
        int r = rowBase + r0 + i;
        if (r < N) {
            unsigned lo = f2bf(accs[i].x) | (f2bf(accs[i].y) << 16);
            unsigned hi = f2bf(accs[i].z) | (f2bf(accs[i].w) << 16);
            *(uint2*)&proj16[(size_t)r * D + c0] = make_uint2(lo, hi);
        }
    }
}

// ---------------------------------------------------------------------------
// fallback path (atomic scatter + fp32 row GEMM) if ws/shape checks fail
// ---------------------------------------------------------------------------
__global__ void scatter_kernel(const int* __restrict__ src, const int* __restrict__ dst,
                               const float* __restrict__ w, const float* __restrict__ data,
                               float* __restrict__ agg, int E) {
    int tid = blockIdx.x * blockDim.x + threadIdx.x;
    int e = tid >> 6;
    int d = tid & 63;
    if (e >= E) return;
    float val = w[e] * data[(size_t)src[e] * D + d];
    atomicAdd(&agg[(size_t)dst[e] * D + d], val);
}

__global__ __launch_bounds__(256, 4) void rowgemm_f32_kernel(const float* __restrict__ A,
                                                             const float* __restrict__ theta,
                                                             float* __restrict__ out, int N) {
    __shared__ float th[D * D];
    __shared__ float at[D][68];
    int t = threadIdx.x;
    int rowBase = blockIdx.x * 64;
#pragma unroll
    for (int i = 0; i < 4; ++i) {
        int f = t + i * 256;
        ((float4*)th)[f] = ((const float4*)theta)[f];
    }
#pragma unroll
    for (int i = 0; i < 4; ++i) {
        int f = t + i * 256;
        int row = f >> 4;
        int kv = f & 15;
        float4 v = make_float4(0.f, 0.f, 0.f, 0.f);
        if (rowBase + row < N) v = *(const float4*)&A[(size_t)(rowBase + row) * D + kv * 4];
        at[kv * 4 + 0][row] = v.x;
        at[kv * 4 + 1][row] = v.y;
        at[kv * 4 + 2][row] = v.z;
        at[kv * 4 + 3][row] = v.w;
    }
    __syncthreads();
    int c0 = (t & 15) * 4;
    int r0 = (t >> 4) * 4;
    float4 acc0 = make_float4(0.f, 0.f, 0.f, 0.f);
    float4 acc1 = acc0, acc2 = acc0, acc3 = acc0;
#pragma unroll 16
    for (int kk = 0; kk < D; ++kk) {
        float4 bv = *(const float4*)&th[kk * D + c0];
        float4 av = *(const float4*)&at[kk][r0];
        acc0.x += av.x * bv.x; acc0.y += av.x * bv.y; acc0.z += av.x * bv.z; acc0.w += av.x * bv.w;
        acc1.x += av.y * bv.x; acc1.y += av.y * bv.y; acc1.z += av.y * bv.z; acc1.w += av.y * bv.w;
        acc2.x += av.z * bv.x; acc2.y += av.z * bv.y; acc2.z += av.z * bv.z; acc2.w += av.z * bv.w;
        acc3.x += av.w * bv.x; acc3.y += av.w * bv.y; acc3.z += av.w * bv.z; acc3.w += av.w * bv.w;
    }
    float4 accs[4] = {acc0, acc1, acc2, acc3};
#pragma unroll
    for (int i = 0; i < 4; ++i) {
        int r = rowBase + r0 + i;
        if (r < N) *(float4*)&out[(size_t)r * D + c0] = accs[i];
    }
}

extern "C" void kernel_launch(void* const* d_in, const int* in_sizes, int n_in,
                              void* d_out, int out_size, void* d_ws, size_t ws_size,
                              hipStream_t stream) {
    const int*   src   = (const int*)d_in[0];
    const int*   dst   = (const int*)d_in[1];
    const float* w     = (const float*)d_in[2];
    const float* data  = (const float*)d_in[3];
    const float* theta = (const float*)d_in[4];
    const int E = in_sizes[0];
    const int N = in_sizes[3] / D;
    float* out = (float*)d_out;

    const int B = (N + NPB - 1) / NPB;

    // ws layout: proj16 (bf16) | adjB | cnt[B] | bucketStart[B+1] | cursor[B]
    size_t projBytes = (size_t)N * D * 2;
    size_t need = projBytes + (size_t)E * 8
                + ((size_t)3 * B + 2) * 4 + 256;

    if (ws_size >= need && N < (1 << 20) && B <= MAXB) {
        unsigned short* proj16 = (unsigned short*)d_ws;
        int2* adjB        = (int2*)((char*)d_ws + projBytes);
        int*  cnt         = (int*)(adjB + E);
        int*  bucketStart = cnt + B;
        int*  cursor      = bucketStart + (B + 1);

        int g = (E + CHUNK_MAX - 1) / CHUNK_MAX;   // guarantees chunk <= CHUNK_MAX

        zero_i_kernel<<<(B + 255) / 256, 256, 0, stream>>>(cnt, B);
        hist_bucket_kernel<<<256, SCATTER_T, 0, stream>>>(dst, cnt, E, B);
        scan_bucket_kernel<<<1, MAXB, 0, stream>>>(cnt, bucketStart, cursor, B, E);
        bucket_scatter_kernel<<<g, SCATTER_T, 0, stream>>>(src, dst, w, cursor, adjB, E, B);
        rowgemm_bf16_kernel<<<(N + 63) / 64, 256, 0, stream>>>(data, theta, proj16, N);
        sort_gather_kernel<<<B, GT, 0, stream>>>(adjB, bucketStart, (const unsigned*)proj16, out, N);
    } else {
        float* agg = (float*)d_ws;
        int n4 = (N * D) / 4;
        zero_f4_kernel<<<(n4 + 255) / 256, 256, 0, stream>>>((float4*)agg, n4);
        long long total = (long long)E * D;
        scatter_kernel<<<(int)((total + 255) / 256), 256, 0, stream>>>(src, dst, w, data, agg, E);
        rowgemm_f32_kernel<<<(N + 63) / 64, 256, 0, stream>>>(agg, theta, out, N);
    }
}

// Round 2
// 163.947 us; speedup vs baseline: 1.2574x; 1.1622x over previous
//
#include <hip/hip_runtime.h>

#define D 64
#define NPB 128              // nodes per bucket (dstLocal: 7 bits)
#define NPB_SHIFT 7
#define MAXB 1024            // bound on bucket count B = ceil(N/NPB)
#define SCATTER_T 512
#define CHUNK_MAX 4704       // max edges staged per scatter block (LDS-sized)
#define CAPB 2560            // fixed per-bucket capacity in adjB (mean 1534)
#define GT 512               // sort_gather block size (8 waves)

// round-to-nearest-even fp32 -> bf16 (values are finite/normal here)
__device__ inline unsigned f2bf(float f) {
    unsigned u = __float_as_uint(f);
    return (u + 0x7FFFu + ((u >> 16) & 1u)) >> 16;
}

// ---------------------------------------------------------------------------
// zero helper (ws is poisoned 0xAA every launch)
// ---------------------------------------------------------------------------
__global__ void zero_i_kernel(int* __restrict__ p, int n) {
    int i = blockIdx.x * blockDim.x + threadIdx.x;
    if (i < n) p[i] = 0;
}
__global__ void zero_f4_kernel(float4* __restrict__ p, int n4) {
    int i = blockIdx.x * blockDim.x + threadIdx.x;
    if (i < n4) p[i] = make_float4(0.f, 0.f, 0.f, 0.f);
}

// ---------------------------------------------------------------------------
// bucket scatter v3: fixed-capacity buckets (no hist/scan prepass).
// Pass A: LDS chunk histogram -> local excl scan (lpre) -> reserve ranges
// directly from per-bucket cursors (base 0, region base = bkt*CAPB).
// Pass B: place packed entries at their locally-sorted LDS slot.
// Pass C: walk local sorted order -> ~48B contiguous runs per bucket.
// Entries whose reserved position >= CAPB go to the overflow list (cold;
// never taken for this input: max bucket ~1700 << 2560).
// Packing: x = src | dstLocal<<20, y = w bits.
// ---------------------------------------------------------------------------
__global__ __launch_bounds__(SCATTER_T) void bucket_scatter_kernel(
        const int* __restrict__ src, const int* __restrict__ dst,
        const float* __restrict__ w, int* __restrict__ cursor,
        int* __restrict__ ovfCnt, int4* __restrict__ ovf,
        int2* __restrict__ adjB, int E, int B) {
    __shared__ int lc[MAXB];
    __shared__ int lpre[MAXB];
    __shared__ int lbase[MAXB];
    __shared__ int lfill[MAXB];
    __shared__ int sums[SCATTER_T];
    __shared__ unsigned short sb[CHUNK_MAX];
    __shared__ int2 stage[CHUNK_MAX];

    int t = threadIdx.x;
    int chunk = (E + gridDim.x - 1) / gridDim.x;   // <= CHUNK_MAX by launch calc
    int lo = blockIdx.x * chunk, hi = min(lo + chunk, E);
    int n = hi - lo;
    if (n <= 0) return;

    for (int i = t; i < MAXB; i += SCATTER_T) { lc[i] = 0; lfill[i] = 0; }
    __syncthreads();

    // A1: histogram of this chunk
    for (int e = lo + t; e < hi; e += SCATTER_T)
        atomicAdd(&lc[dst[e] >> NPB_SHIFT], 1);
    __syncthreads();

    // A2: exclusive scan of lc[0..MAXB) (2 elems/thread + H-S on 512)
    int s0 = lc[2 * t], s1 = lc[2 * t + 1];
    sums[t] = s0 + s1;
    __syncthreads();
    for (int st = 1; st < SCATTER_T; st <<= 1) {
        int v = (t >= st) ? sums[t - st] : 0;
        __syncthreads();
        sums[t] += v;
        __syncthreads();
    }
    int ex = (t == 0) ? 0 : sums[t - 1];
    lpre[2 * t]     = ex;
    lpre[2 * t + 1] = ex + s0;
    __syncthreads();

    // A3: reserve per-bucket ranges (1 global atomic per nonempty bucket)
    for (int i = t; i < B; i += SCATTER_T) {
        int c = lc[i];
        lbase[i] = c ? atomicAdd(&cursor[i], c) : 0;
    }
    __syncthreads();

    // B: place into locally-sorted LDS slots
    for (int e = lo + t; e < hi; e += SCATTER_T) {
        int d = dst[e];
        int bkt = d >> NPB_SHIFT;
        int i = lpre[bkt] + atomicAdd(&lfill[bkt], 1);
        stage[i] = make_int2(src[e] | ((d & (NPB - 1)) << 20), __float_as_int(w[e]));
        sb[i] = (unsigned short)bkt;
    }
    __syncthreads();

    // C: coalesced write-out in locally-sorted order
    for (int i = t; i < n; i += SCATTER_T) {
        int bkt = sb[i];
        int2 v = stage[i];
        int pos = lbase[bkt] + (i - lpre[bkt]);
        if (pos < CAPB) {
            adjB[(size_t)bkt * CAPB + pos] = v;
        } else {                                   // cold: bucket overflow
            int oi = atomicAdd(ovfCnt, 1);
            ovf[oi] = make_int4(v.x, v.y, bkt, 0);
        }
    }
}

// ---------------------------------------------------------------------------
// fused sort+gather: one block per bucket. Counting-sort the bucket's adjB
// slice into LDS (node-grouped), then each wave gathers 16 nodes:
// adjacency via LDS broadcast reads, proj rows 128B/half-wave from L2/L3,
// 2-edge ILP, cross-half shfl reduce, coalesced float2 row store.
// Overflow entries (cursor > CAPB, never for this input) are drained with
// global float atomics after the block's own stores (syncthreads orders).
// ---------------------------------------------------------------------------
__global__ __launch_bounds__(GT) void sort_gather_kernel(
        const int2* __restrict__ adjB, const int* __restrict__ cursor,
        const int* __restrict__ ovfCnt, const int4* __restrict__ ovf,
        const unsigned* __restrict__ projU, float* __restrict__ out, int N) {
    __shared__ int cnt[NPB];
    __shared__ int pre[NPB];
    __shared__ int fill[NPB];
    __shared__ int2 ladj[CAPB];
    __shared__ int sOvf;

    int b = blockIdx.x;
    int t = threadIdx.x;
    int total = cursor[b];
    int m = min(total, CAPB);
    const int2* base = adjB + (size_t)b * CAPB;

    if (t < NPB) { cnt[t] = 0; fill[t] = 0; }
    if (t == 0) sOvf = *ovfCnt;
    __syncthreads();
    for (int e = t; e < m; e += GT)
        atomicAdd(&cnt[((unsigned)base[e].x) >> 20], 1);
    __syncthreads();
    if (t < NPB) pre[t] = cnt[t];
    __syncthreads();
    for (int st = 1; st < NPB; st <<= 1) {
        int v = (t < NPB && t >= st) ? pre[t - st] : 0;
        __syncthreads();
        if (t < NPB) pre[t] += v;
        __syncthreads();
    }
    for (int e = t; e < m; e += GT) {
        int2 a = base[e];
        int dL = ((unsigned)a.x) >> 20;
        int pos = ((dL == 0) ? 0 : pre[dL - 1]) + atomicAdd(&fill[dL], 1);
        ladj[pos] = make_int2(a.x & 0xFFFFF, a.y);
    }
    __syncthreads();

    int wave = t >> 6;          // 0..7
    int lane = t & 63;
    int half = lane >> 5;
    int k = lane & 31;          // lane owns dims {2k, 2k+1}

#pragma unroll 1
    for (int i = 0; i < NPB / 8; ++i) {      // 16 nodes per wave
        int dL = wave * (NPB / 8) + i;
        int node = b * NPB + dL;
        if (node >= N) break;                // wave-uniform
        int rb = (dL == 0) ? 0 : pre[dL - 1];
        int re = pre[dL];
        float2 accA = make_float2(0.f, 0.f);
        float2 accB = make_float2(0.f, 0.f);
        int j = rb + half;
        for (; j + 2 < re; j += 4) {         // 2 edges in flight per half
            int2 a0 = ladj[j];
            int2 a1 = ladj[j + 2];
            float w0 = __int_as_float(a0.y);
            float w1 = __int_as_float(a1.y);
            unsigned p0 = projU[(size_t)a0.x * 32 + k];
            unsigned p1 = projU[(size_t)a1.x * 32 + k];
            accA.x += w0 * __uint_as_float(p0 << 16);
            accA.y += w0 * __uint_as_float(p0 & 0xFFFF0000u);
            accB.x += w1 * __uint_as_float(p1 << 16);
            accB.y += w1 * __uint_as_float(p1 & 0xFFFF0000u);
        }
        if (j < re) {
            int2 a0 = ladj[j];
            float w0 = __int_as_float(a0.y);
            unsigned p0 = projU[(size_t)a0.x * 32 + k];
            accA.x += w0 * __uint_as_float(p0 << 16);
            accA.y += w0 * __uint_as_float(p0 & 0xFFFF0000u);
        }
        float2 acc = make_float2(accA.x + accB.x, accA.y + accB.y);
        acc.x += __shfl(acc.x, lane ^ 32, 64);
        acc.y += __shfl(acc.y, lane ^ 32, 64);
        if (half == 0)
            *(float2*)&out[(size_t)node * D + 2 * k] = acc;  // 32 lanes x 8B
    }

    if (sOvf > 0) {                           // insurance path, never hot
        __syncthreads();                      // order our stores before atomics
        for (int e = t; e < sOvf; e += GT) {
            int4 o = ovf[e];
            if (o.z != b) continue;
            int dL = ((unsigned)o.x) >> 20;
            int node = b * NPB + dL;
            if (node >= N) continue;
            float wgt = __int_as_float(o.y);
            int s = o.x & 0xFFFFF;
            for (int d2 = 0; d2 < D / 2; ++d2) {
                unsigned p = projU[(size_t)s * 32 + d2];
                atomicAdd(&out[(size_t)node * D + 2 * d2],     wgt * __uint_as_float(p << 16));
                atomicAdd(&out[(size_t)node * D + 2 * d2 + 1], wgt * __uint_as_float(p & 0xFFFF0000u));
            }
        }
    }
}

// ---------------------------------------------------------------------------
// Tiled row GEMM -> bf16 packed proj. Block = 64 rows; A staged transposed
// in LDS; theta in LDS; thread computes 4x4 block.
// __launch_bounds__(256,4): cap VGPR at 128 (r5 post-mortem: the bf16-pack
// epilogue made the scheduler hoist the full k-unroll -> 252 VGPR, 9%
// occupancy, 60us). unroll 16 keeps ILP within the cap without spilling.
// ---------------------------------------------------------------------------
__global__ __launch_bounds__(256, 4) void rowgemm_bf16_kernel(const float* __restrict__ A,
                                                              const float* __restrict__ theta,
                                                              unsigned short* __restrict__ proj16,
                                                              int N) {
    __shared__ float th[D * D];
    __shared__ float at[D][68];
    int t = threadIdx.x;
    int rowBase = blockIdx.x * 64;

#pragma unroll
    for (int i = 0; i < 4; ++i) {
        int f = t + i * 256;
        ((float4*)th)[f] = ((const float4*)theta)[f];
    }
#pragma unroll
    for (int i = 0; i < 4; ++i) {
        int f = t + i * 256;
        int row = f >> 4;
        int kv = f & 15;
        float4 v = make_float4(0.f, 0.f, 0.f, 0.f);
        if (rowBase + row < N) v = *(const float4*)&A[(size_t)(rowBase + row) * D + kv * 4];
        at[kv * 4 + 0][row] = v.x;
        at[kv * 4 + 1][row] = v.y;
        at[kv * 4 + 2][row] = v.z;
        at[kv * 4 + 3][row] = v.w;
    }
    __syncthreads();

    int c0 = (t & 15) * 4;
    int r0 = (t >> 4) * 4;
    float4 acc0 = make_float4(0.f, 0.f, 0.f, 0.f);
    float4 acc1 = acc0, acc2 = acc0, acc3 = acc0;

#pragma unroll 16
    for (int k = 0; k < D; ++k) {
        float4 bv = *(const float4*)&th[k * D + c0];
        float4 av = *(const float4*)&at[k][r0];
        acc0.x += av.x * bv.x; acc0.y += av.x * bv.y; acc0.z += av.x * bv.z; acc0.w += av.x * bv.w;
        acc1.x += av.y * bv.x; acc1.y += av.y * bv.y; acc1.z += av.y * bv.z; acc1.w += av.y * bv.w;
        acc2.x += av.z * bv.x; acc2.y += av.z * bv.y; acc2.z += av.z * bv.z; acc2.w += av.z * bv.w;
        acc3.x += av.w * bv.x; acc3.y += av.w * bv.y; acc3.z += av.w * bv.z; acc3.w += av.w * bv.w;
    }

    float4 accs[4] = {acc0, acc1, acc2, acc3};
#pragma unroll
    for (int i = 0; i < 4; ++i) {
        int r = rowBase + r0 + i;
        if (r < N) {
            unsigned lo = f2bf(accs[i].x) | (f2bf(accs[i].y) << 16);
            unsigned hi = f2bf(accs[i].z) | (f2bf(accs[i].w) << 16);
            *(uint2*)&proj16[(size_t)r * D + c0] = make_uint2(lo, hi);
        }
    }
}

// ---------------------------------------------------------------------------
// fallback path (atomic scatter + fp32 row GEMM) if ws/shape checks fail
// ---------------------------------------------------------------------------
__global__ void scatter_kernel(const int* __restrict__ src, const int* __restrict__ dst,
                               const float* __restrict__ w, const float* __restrict__ data,
                               float* __restrict__ agg, int E) {
    int tid = blockIdx.x * blockDim.x + threadIdx.x;
    int e = tid >> 6;
    int d = tid & 63;
    if (e >= E) return;
    float val = w[e] * data[(size_t)src[e] * D + d];
    atomicAdd(&agg[(size_t)dst[e] * D + d], val);
}

__global__ __launch_bounds__(256, 4) void rowgemm_f32_kernel(const float* __restrict__ A,
                                                             const float* __restrict__ theta,
                                                             float* __restrict__ out, int N) {
    __shared__ float th[D * D];
    __shared__ float at[D][68];
    int t = threadIdx.x;
    int rowBase = blockIdx.x * 64;
#pragma unroll
    for (int i = 0; i < 4; ++i) {
        int f = t + i * 256;
        ((float4*)th)[f] = ((const float4*)theta)[f];
    }
#pragma unroll
    for (int i = 0; i < 4; ++i) {
        int f = t + i * 256;
        int row = f >> 4;
        int kv = f & 15;
        float4 v = make_float4(0.f, 0.f, 0.f, 0.f);
        if (rowBase + row < N) v = *(const float4*)&A[(size_t)(rowBase + row) * D + kv * 4];
        at[kv * 4 + 0][row] = v.x;
        at[kv * 4 + 1][row] = v.y;
        at[kv * 4 + 2][row] = v.z;
        at[kv * 4 + 3][row] = v.w;
    }
    __syncthreads();
    int c0 = (t & 15) * 4;
    int r0 = (t >> 4) * 4;
    float4 acc0 = make_float4(0.f, 0.f, 0.f, 0.f);
    float4 acc1 = acc0, acc2 = acc0, acc3 = acc0;
#pragma unroll 16
    for (int kk = 0; kk < D; ++kk) {
        float4 bv = *(const float4*)&th[kk * D + c0];
        float4 av = *(const float4*)&at[kk][r0];
        acc0.x += av.x * bv.x; acc0.y += av.x * bv.y; acc0.z += av.x * bv.z; acc0.w += av.x * bv.w;
        acc1.x += av.y * bv.x; acc1.y += av.y * bv.y; acc1.z += av.y * bv.z; acc1.w += av.y * bv.w;
        acc2.x += av.z * bv.x; acc2.y += av.z * bv.y; acc2.z += av.z * bv.z; acc2.w += av.z * bv.w;
        acc3.x += av.w * bv.x; acc3.y += av.w * bv.y; acc3.z += av.w * bv.z; acc3.w += av.w * bv.w;
    }
    float4 accs[4] = {acc0, acc1, acc2, acc3};
#pragma unroll
    for (int i = 0; i < 4; ++i) {
        int r = rowBase + r0 + i;
        if (r < N) *(float4*)&out[(size_t)r * D + c0] = accs[i];
    }
}

extern "C" void kernel_launch(void* const* d_in, const int* in_sizes, int n_in,
                              void* d_out, int out_size, void* d_ws, size_t ws_size,
                              hipStream_t stream) {
    const int*   src   = (const int*)d_in[0];
    const int*   dst   = (const int*)d_in[1];
    const float* w     = (const float*)d_in[2];
    const float* data  = (const float*)d_in[3];
    const float* theta = (const float*)d_in[4];
    const int E = in_sizes[0];
    const int N = in_sizes[3] / D;
    float* out = (float*)d_out;

    const int B = (N + NPB - 1) / NPB;

    // ws layout: proj16 (bf16) | adjB (B*CAPB int2) | ovf (E int4) |
    //            cursor[B] | ovfCnt
    size_t projBytes = (size_t)N * D * 2;
    size_t adjBytes  = (size_t)B * CAPB * 8;
    size_t ovfBytes  = (size_t)E * 16;
    size_t need = projBytes + adjBytes + ovfBytes + ((size_t)B + 1) * 4 + 256;

    if (ws_size >= need && N < (1 << 20) && B <= MAXB) {
        unsigned short* proj16 = (unsigned short*)d_ws;
        int2* adjB   = (int2*)((char*)d_ws + projBytes);
        int4* ovf    = (int4*)((char*)d_ws + projBytes + adjBytes);
        int*  cursor = (int*)((char*)d_ws + projBytes + adjBytes + ovfBytes);
        int*  ovfCnt = cursor + B;

        int g = (E + CHUNK_MAX - 1) / CHUNK_MAX;   // guarantees chunk <= CHUNK_MAX

        zero_i_kernel<<<(B + 1 + 255) / 256, 256, 0, stream>>>(cursor, B + 1);
        bucket_scatter_kernel<<<g, SCATTER_T, 0, stream>>>(src, dst, w, cursor, ovfCnt, ovf, adjB, E, B);
        rowgemm_bf16_kernel<<<(N + 63) / 64, 256, 0, stream>>>(data, theta, proj16, N);
        sort_gather_kernel<<<B, GT, 0, stream>>>(adjB, cursor, ovfCnt, ovf, (const unsigned*)proj16, out, N);
    } else {
        float* agg = (float*)d_ws;
        int n4 = (N * D) / 4;
        zero_f4_kernel<<<(n4 + 255) / 256, 256, 0, stream>>>((float4*)agg, n4);
        long long total = (long long)E * D;
        scatter_kernel<<<(int)((total + 255) / 256), 256, 0, stream>>>(src, dst, w, data, agg, E);
        rowgemm_f32_kernel<<<(N + 63) / 64, 256, 0, stream>>>(agg, theta, out, N);
    }
}

// Round 3
// 161.426 us; speedup vs baseline: 1.2770x; 1.0156x over previous
//
#include <hip/hip_runtime.h>

#define D 64
#define NPB 128              // nodes per bucket (dstLocal: 7 bits)
#define NPB_SHIFT 7
#define MAXB 1024            // bound on bucket count B = ceil(N/NPB)
#define SCATTER_T 512
#define CHUNK_MAX 4704       // max edges staged per scatter block (LDS-sized)
#define SCQ 10               // per-thread reg-staged edges (SCQ*512 >= CHUNK_MAX)
#define CAPB 2560            // fixed per-bucket capacity in adjB (mean 1534)
#define GT 512               // sort_gather block size (8 waves)
#define GQ 5                 // per-thread reg-staged bucket entries (GQ*GT >= CAPB)

// round-to-nearest-even fp32 -> bf16 (values are finite/normal here)
__device__ inline unsigned f2bf(float f) {
    unsigned u = __float_as_uint(f);
    return (u + 0x7FFFu + ((u >> 16) & 1u)) >> 16;
}

// ---------------------------------------------------------------------------
// zero helper (ws is poisoned 0xAA every launch)
// ---------------------------------------------------------------------------
__global__ void zero_i_kernel(int* __restrict__ p, int n) {
    int i = blockIdx.x * blockDim.x + threadIdx.x;
    if (i < n) p[i] = 0;
}
__global__ void zero_f4_kernel(float4* __restrict__ p, int n4) {
    int i = blockIdx.x * blockDim.x + threadIdx.x;
    if (i < n4) p[i] = make_float4(0.f, 0.f, 0.f, 0.f);
}

// ---------------------------------------------------------------------------
// fused scatter + rowgemm: blocks [0,gs) bucket-scatter edges; blocks
// [gs, gs+gg) project data->proj16 (bf16). The two are data-independent;
// fusing overlaps scatter's LDS-atomic/latency phase with gemm's FMA/BW
// phase. LDS is a union (64KB) -> 2 blocks/CU, 16 waves/CU either way.
// ---------------------------------------------------------------------------
union FusedSMem {
    struct {
        int lc[MAXB];
        int lpre[MAXB];
        int lbase[MAXB];
        int lfill[MAXB];
        int sums[SCATTER_T];
        unsigned short sb[CHUNK_MAX];
        int2 stage[CHUNK_MAX];        // 8B-aligned offset (27840 % 8 == 0)
    } sc;
    struct {
        float th[D * D];
        float at[D][68];
    } gm;
};

__global__ __launch_bounds__(SCATTER_T, 4) void fused_scatter_gemm_kernel(
        const int* __restrict__ src, const int* __restrict__ dst,
        const float* __restrict__ w, const float* __restrict__ data,
        const float* __restrict__ theta, int* __restrict__ cursor,
        int* __restrict__ ovfCnt, int4* __restrict__ ovf,
        int2* __restrict__ adjB, unsigned short* __restrict__ proj16,
        int E, int B, int N, int gs) {
    __shared__ FusedSMem sm;
    int t = threadIdx.x;

    if ((int)blockIdx.x < gs) {
        // ----------------- scatter body -----------------
        int chunk = (E + gs - 1) / gs;             // <= CHUNK_MAX by host calc
        int lo = blockIdx.x * chunk, hi = min(lo + chunk, E);
        if (hi - lo <= 0) return;
        int n = hi - lo;

        for (int i = t; i < MAXB; i += SCATTER_T) { sm.sc.lc[i] = 0; sm.sc.lfill[i] = 0; }

        // reg-stage this thread's edges (one global pass over dst/src/w)
        int rd[SCQ]; int rs[SCQ]; float rw[SCQ];
#pragma unroll
        for (int q = 0; q < SCQ; ++q) {
            int e = lo + t + q * SCATTER_T;
            bool v = e < hi;
            rd[q] = v ? dst[e] : -1;
            rs[q] = v ? src[e] : 0;
            rw[q] = v ? w[e] : 0.f;
        }
        __syncthreads();

        // A1: chunk histogram
#pragma unroll
        for (int q = 0; q < SCQ; ++q)
            if (rd[q] >= 0) atomicAdd(&sm.sc.lc[rd[q] >> NPB_SHIFT], 1);
        __syncthreads();

        // A2: exclusive scan of lc[0..MAXB) (2/thread + H-S on 512)
        int s0 = sm.sc.lc[2 * t], s1 = sm.sc.lc[2 * t + 1];
        sm.sc.sums[t] = s0 + s1;
        __syncthreads();
        for (int st = 1; st < SCATTER_T; st <<= 1) {
            int v = (t >= st) ? sm.sc.sums[t - st] : 0;
            __syncthreads();
            sm.sc.sums[t] += v;
            __syncthreads();
        }
        int ex = (t == 0) ? 0 : sm.sc.sums[t - 1];
        sm.sc.lpre[2 * t] = ex;
        sm.sc.lpre[2 * t + 1] = ex + s0;
        __syncthreads();

        // A3: reserve per-bucket ranges (1 global atomic per nonempty bucket)
        for (int i = t; i < B; i += SCATTER_T) {
            int c = sm.sc.lc[i];
            sm.sc.lbase[i] = c ? atomicAdd(&cursor[i], c) : 0;
        }
        __syncthreads();

        // B: place into locally-sorted LDS slots
#pragma unroll
        for (int q = 0; q < SCQ; ++q) {
            int d = rd[q];
            if (d >= 0) {
                int bkt = d >> NPB_SHIFT;
                int i = sm.sc.lpre[bkt] + atomicAdd(&sm.sc.lfill[bkt], 1);
                sm.sc.stage[i] = make_int2(rs[q] | ((d & (NPB - 1)) << 20),
                                           __float_as_int(rw[q]));
                sm.sc.sb[i] = (unsigned short)bkt;
            }
        }
        __syncthreads();

        // C: coalesced write-out in locally-sorted order
        for (int i = t; i < n; i += SCATTER_T) {
            int bkt = sm.sc.sb[i];
            int2 v = sm.sc.stage[i];
            int pos = sm.sc.lbase[bkt] + (i - sm.sc.lpre[bkt]);
            if (pos < CAPB) {
                adjB[(size_t)bkt * CAPB + pos] = v;
            } else {                               // cold: bucket overflow
                int oi = atomicAdd(ovfCnt, 1);
                ovf[oi] = make_int4(v.x, v.y, bkt, 0);
            }
        }
    } else {
        // ----------------- rowgemm body (512 thr, 64-row tile) -----------------
        int gb = blockIdx.x - gs;
        int rowBase = gb * 64;

#pragma unroll
        for (int i = 0; i < 2; ++i) {
            int f = t + i * 512;
            ((float4*)sm.gm.th)[f] = ((const float4*)theta)[f];
        }
#pragma unroll
        for (int i = 0; i < 2; ++i) {
            int f = t + i * 512;
            int row = f >> 4;
            int kv = f & 15;
            float4 v = make_float4(0.f, 0.f, 0.f, 0.f);
            if (rowBase + row < N) v = *(const float4*)&data[(size_t)(rowBase + row) * D + kv * 4];
            sm.gm.at[kv * 4 + 0][row] = v.x;
            sm.gm.at[kv * 4 + 1][row] = v.y;
            sm.gm.at[kv * 4 + 2][row] = v.z;
            sm.gm.at[kv * 4 + 3][row] = v.w;
        }
        __syncthreads();

        int c0 = (t & 15) * 4;
        int r0 = (t >> 4) * 2;
        float4 acc0 = make_float4(0.f, 0.f, 0.f, 0.f);
        float4 acc1 = acc0;

#pragma unroll 16
        for (int k = 0; k < D; ++k) {
            float4 bv = *(const float4*)&sm.gm.th[k * D + c0];
            float a0 = sm.gm.at[k][r0];
            float a1 = sm.gm.at[k][r0 + 1];
            acc0.x += a0 * bv.x; acc0.y += a0 * bv.y; acc0.z += a0 * bv.z; acc0.w += a0 * bv.w;
            acc1.x += a1 * bv.x; acc1.y += a1 * bv.y; acc1.z += a1 * bv.z; acc1.w += a1 * bv.w;
        }

        int r = rowBase + r0;
        if (r < N) {
            unsigned lo16 = f2bf(acc0.x) | (f2bf(acc0.y) << 16);
            unsigned hi16 = f2bf(acc0.z) | (f2bf(acc0.w) << 16);
            *(uint2*)&proj16[(size_t)r * D + c0] = make_uint2(lo16, hi16);
        }
        if (r + 1 < N) {
            unsigned lo16 = f2bf(acc1.x) | (f2bf(acc1.y) << 16);
            unsigned hi16 = f2bf(acc1.z) | (f2bf(acc1.w) << 16);
            *(uint2*)&proj16[(size_t)(r + 1) * D + c0] = make_uint2(lo16, hi16);
        }
    }
}

// ---------------------------------------------------------------------------
// fused sort+gather: one block per bucket. Single global pass stages the
// bucket's adjB slice into registers while counting; after the scan each
// thread places its staged entries node-grouped into LDS. Gather: each
// HALF-WAVE owns a node (4-deep edge ILP -> 8 proj loads in flight/wave),
// adjacency via LDS broadcast, proj rows 128B/half from L2/L3, own 256B
// row store per half (no cross-half reduce).
// Overflow entries (cursor > CAPB, never for this input) drained with
// global float atomics after the block's own stores.
// ---------------------------------------------------------------------------
__global__ __launch_bounds__(GT) void sort_gather_kernel(
        const int2* __restrict__ adjB, const int* __restrict__ cursor,
        const int* __restrict__ ovfCnt, const int4* __restrict__ ovf,
        const unsigned* __restrict__ projU, float* __restrict__ out, int N) {
    __shared__ int cnt[NPB];
    __shared__ int pre[NPB];
    __shared__ int fill[NPB];
    __shared__ int2 ladj[CAPB];
    __shared__ int sOvf;

    int b = blockIdx.x;
    int t = threadIdx.x;
    int total = cursor[b];
    int m = min(total, CAPB);
    const int2* base = adjB + (size_t)b * CAPB;

    if (t < NPB) { cnt[t] = 0; fill[t] = 0; }
    if (t == 0) sOvf = *ovfCnt;
    __syncthreads();

    // single global pass: reg-stage + histogram
    int2 r[GQ];
#pragma unroll
    for (int q = 0; q < GQ; ++q) {
        int e = t + q * GT;
        if (e < m) {
            int2 a = base[e];
            r[q] = a;
            atomicAdd(&cnt[((unsigned)a.x) >> 20], 1);
        }
    }
    __syncthreads();
    if (t < NPB) pre[t] = cnt[t];
    __syncthreads();
    for (int st = 1; st < NPB; st <<= 1) {
        int v = (t < NPB && t >= st) ? pre[t - st] : 0;
        __syncthreads();
        if (t < NPB) pre[t] += v;
        __syncthreads();
    }
    // place node-grouped into LDS from registers
#pragma unroll
    for (int q = 0; q < GQ; ++q) {
        int e = t + q * GT;
        if (e < m) {
            int2 a = r[q];
            int dL = ((unsigned)a.x) >> 20;
            int pos = ((dL == 0) ? 0 : pre[dL - 1]) + atomicAdd(&fill[dL], 1);
            ladj[pos] = make_int2(a.x & 0xFFFFF, a.y);
        }
    }
    __syncthreads();

    int wave = t >> 6;          // 0..7
    int lane = t & 63;
    int half = lane >> 5;
    int k = lane & 31;          // lane owns dims {2k, 2k+1} of its half's node

#pragma unroll 1
    for (int i = 0; i < 8; ++i) {            // 2 nodes per wave-iter
        int dL = wave * 16 + i * 2 + half;
        int node = b * NPB + dL;
        if (node < N) {
            int rb = (dL == 0) ? 0 : pre[dL - 1];
            int re = pre[dL];
            float2 accA = make_float2(0.f, 0.f);
            float2 accB = make_float2(0.f, 0.f);
            int j = rb;
            for (; j + 3 < re; j += 4) {     // 4 proj loads in flight per half
                int2 a0 = ladj[j];
                int2 a1 = ladj[j + 1];
                int2 a2 = ladj[j + 2];
                int2 a3 = ladj[j + 3];
                unsigned p0 = projU[(size_t)a0.x * 32 + k];
                unsigned p1 = projU[(size_t)a1.x * 32 + k];
                unsigned p2 = projU[(size_t)a2.x * 32 + k];
                unsigned p3 = projU[(size_t)a3.x * 32 + k];
                float w0 = __int_as_float(a0.y), w1 = __int_as_float(a1.y);
                float w2 = __int_as_float(a2.y), w3 = __int_as_float(a3.y);
                accA.x += w0 * __uint_as_float(p0 << 16);
                accA.y += w0 * __uint_as_float(p0 & 0xFFFF0000u);
                accB.x += w1 * __uint_as_float(p1 << 16);
                accB.y += w1 * __uint_as_float(p1 & 0xFFFF0000u);
                accA.x += w2 * __uint_as_float(p2 << 16);
                accA.y += w2 * __uint_as_float(p2 & 0xFFFF0000u);
                accB.x += w3 * __uint_as_float(p3 << 16);
                accB.y += w3 * __uint_as_float(p3 & 0xFFFF0000u);
            }
            for (; j < re; ++j) {
                int2 a0 = ladj[j];
                float w0 = __int_as_float(a0.y);
                unsigned p0 = projU[(size_t)a0.x * 32 + k];
                accA.x += w0 * __uint_as_float(p0 << 16);
                accA.y += w0 * __uint_as_float(p0 & 0xFFFF0000u);
            }
            float2 acc = make_float2(accA.x + accB.x, accA.y + accB.y);
            *(float2*)&out[(size_t)node * D + 2 * k] = acc;  // 32 lanes x 8B
        }
    }

    if (sOvf > 0) {                           // insurance path, never hot
        __syncthreads();                      // order our stores before atomics
        for (int e = t; e < sOvf; e += GT) {
            int4 o = ovf[e];
            if (o.z != b) continue;
            int dL = ((unsigned)o.x) >> 20;
            int node = b * NPB + dL;
            if (node >= N) continue;
            float wgt = __int_as_float(o.y);
            int s = o.x & 0xFFFFF;
            for (int d2 = 0; d2 < D / 2; ++d2) {
                unsigned p = projU[(size_t)s * 32 + d2];
                atomicAdd(&out[(size_t)node * D + 2 * d2],     wgt * __uint_as_float(p << 16));
                atomicAdd(&out[(size_t)node * D + 2 * d2 + 1], wgt * __uint_as_float(p & 0xFFFF0000u));
            }
        }
    }
}

// ---------------------------------------------------------------------------
// fallback path (atomic scatter + fp32 row GEMM) if ws/shape checks fail
// ---------------------------------------------------------------------------
__global__ void scatter_kernel(const int* __restrict__ src, const int* __restrict__ dst,
                               const float* __restrict__ w, const float* __restrict__ data,
                               float* __restrict__ agg, int E) {
    int tid = blockIdx.x * blockDim.x + threadIdx.x;
    int e = tid >> 6;
    int d = tid & 63;
    if (e >= E) return;
    float val = w[e] * data[(size_t)src[e] * D + d];
    atomicAdd(&agg[(size_t)dst[e] * D + d], val);
}

__global__ __launch_bounds__(256, 4) void rowgemm_f32_kernel(const float* __restrict__ A,
                                                             const float* __restrict__ theta,
                                                             float* __restrict__ out, int N) {
    __shared__ float th[D * D];
    __shared__ float at[D][68];
    int t = threadIdx.x;
    int rowBase = blockIdx.x * 64;
#pragma unroll
    for (int i = 0; i < 4; ++i) {
        int f = t + i * 256;
        ((float4*)th)[f] = ((const float4*)theta)[f];
    }
#pragma unroll
    for (int i = 0; i < 4; ++i) {
        int f = t + i * 256;
        int row = f >> 4;
        int kv = f & 15;
        float4 v = make_float4(0.f, 0.f, 0.f, 0.f);
        if (rowBase + row < N) v = *(const float4*)&A[(size_t)(rowBase + row) * D + kv * 4];
        at[kv * 4 + 0][row] = v.x;
        at[kv * 4 + 1][row] = v.y;
        at[kv * 4 + 2][row] = v.z;
        at[kv * 4 + 3][row] = v.w;
    }
    __syncthreads();
    int c0 = (t & 15) * 4;
    int r0 = (t >> 4) * 4;
    float4 acc0 = make_float4(0.f, 0.f, 0.f, 0.f);
    float4 acc1 = acc0, acc2 = acc0, acc3 = acc0;
#pragma unroll 16
    for (int kk = 0; kk < D; ++kk) {
        float4 bv = *(const float4*)&th[kk * D + c0];
        float4 av = *(const float4*)&at[kk][r0];
        acc0.x += av.x * bv.x; acc0.y += av.x * bv.y; acc0.z += av.x * bv.z; acc0.w += av.x * bv.w;
        acc1.x += av.y * bv.x; acc1.y += av.y * bv.y; acc1.z += av.y * bv.z; acc1.w += av.y * bv.w;
        acc2.x += av.z * bv.x; acc2.y += av.z * bv.y; acc2.z += av.z * bv.z; acc2.w += av.z * bv.w;
        acc3.x += av.w * bv.x; acc3.y += av.w * bv.y; acc3.z += av.w * bv.z; acc3.w += av.w * bv.w;
    }
    float4 accs[4] = {acc0, acc1, acc2, acc3};
#pragma unroll
    for (int i = 0; i < 4; ++i) {
        int r = rowBase + r0 + i;
        if (r < N) *(float4*)&out[(size_t)r * D + c0] = accs[i];
    }
}

extern "C" void kernel_launch(void* const* d_in, const int* in_sizes, int n_in,
                              void* d_out, int out_size, void* d_ws, size_t ws_size,
                              hipStream_t stream) {
    const int*   src   = (const int*)d_in[0];
    const int*   dst   = (const int*)d_in[1];
    const float* w     = (const float*)d_in[2];
    const float* data  = (const float*)d_in[3];
    const float* theta = (const float*)d_in[4];
    const int E = in_sizes[0];
    const int N = in_sizes[3] / D;
    float* out = (float*)d_out;

    const int B = (N + NPB - 1) / NPB;

    // ws layout: proj16 (bf16) | adjB (B*CAPB int2) | ovf (E int4) |
    //            cursor[B] | ovfCnt
    size_t projBytes = (size_t)N * D * 2;
    size_t adjBytes  = (size_t)B * CAPB * 8;
    size_t ovfBytes  = (size_t)E * 16;
    size_t need = projBytes + adjBytes + ovfBytes + ((size_t)B + 1) * 4 + 256;

    if (ws_size >= need && N < (1 << 20) && B <= MAXB) {
        unsigned short* proj16 = (unsigned short*)d_ws;
        int2* adjB   = (int2*)((char*)d_ws + projBytes);
        int4* ovf    = (int4*)((char*)d_ws + projBytes + adjBytes);
        int*  cursor = (int*)((char*)d_ws + projBytes + adjBytes + ovfBytes);
        int*  ovfCnt = cursor + B;

        int gs = (E + CHUNK_MAX - 1) / CHUNK_MAX;  // chunk <= CHUNK_MAX
        if (gs < 256) gs = 256;                    // one scatter block per CU
        int gg = (N + 63) / 64;

        zero_i_kernel<<<(B + 1 + 255) / 256, 256, 0, stream>>>(cursor, B + 1);
        fused_scatter_gemm_kernel<<<gs + gg, SCATTER_T, 0, stream>>>(
            src, dst, w, data, theta, cursor, ovfCnt, ovf, adjB, proj16, E, B, N, gs);
        sort_gather_kernel<<<B, GT, 0, stream>>>(adjB, cursor, ovfCnt, ovf,
                                                 (const unsigned*)proj16, out, N);
    } else {
        float* agg = (float*)d_ws;
        int n4 = (N * D) / 4;
        zero_f4_kernel<<<(n4 + 255) / 256, 256, 0, stream>>>((float4*)agg, n4);
        long long total = (long long)E * D;
        scatter_kernel<<<(int)((total + 255) / 256), 256, 0, stream>>>(src, dst, w, data, agg, E);
        rowgemm_f32_kernel<<<(N + 63) / 64, 256, 0, stream>>>(agg, theta, out, N);
    }
}